// Round 8
// baseline (163.696 us; speedup 1.0000x reference)
//
#include <hip/hip_runtime.h>

// NormEMAVectorQuantizer on MI355X (gfx950)
// N=8192 tokens, C=32, K=8192 codes, B=32, H*W=256.
// R8: single MFMA sweep. k_prep pre-converts zn/emb to bf16 ONCE. k_max:
// bf16-MFMA scan -> pmax[chunk][tok] (direct stores). k_gmax: per-token
// global max over 32 partials; qualifying CHUNKS (pmax >= gmax-eps) go to a
// worklist (block-aggregated count -> 1 atomicAdd/block). k_rescore: block
// per (tok,chunk) entry, 256 threads = 256 codes, exact fp32 dots, block
// u64-key max -> 1 atomicMax/entry on packed[tok]. Certificate: chunk of
// the fp32 argmax always qualifies (bf16 dot err <= 2*2^-9 = 0.0078 < 0.01
// for unit rows); every equal-max code is rescored -> numpy tie-break exact.
//
// Outputs (float32, concatenated):
//   [0 .. 262144)        z_q_out [B,C,H,W]
//   [262144]             loss (scalar)
//   [262145 .. 270337)   token_ids [B,H,W] as float
//   [270337 .. 532481)   new_embedding [K,C]
//   [532481 .. 540673)   new_cluster_sizes [K]

#define NTOK   8192
#define NCODE  8192
#define CDIM   32
#define HW     256
#define DECAYF 0.99f
#define EPSF   0.01f

#define OUT_ZQ   0
#define OUT_LOSS 262144
#define OUT_IDS  262145
#define OUT_EMB  270337
#define OUT_CS   532481

// workspace byte offsets
#define WS_ZN     0u        // zn row-major [N,C] f32   = 1048576
#define WS_ZNBF   1048576u  // bf16 [N,C]               = 524288
#define WS_EBF    1572864u  // bf16 [K,C]               = 524288
#define WS_PMAX   2097152u  // f32 [32][N]              = 1048576
#define WS_PACK   3145728u  // u64 [N]                  = 65536   <- zeroed
#define WS_BINS   3211264u  // i32 [K]                  = 32768
#define WS_LOSSP  3244032u  // f32 [64]                 = 256
#define WS_CNT    3244288u  // u32                      = 4
#define WS_ZEND   3244292u
#define WS_ZERO_BYTES (WS_ZEND - WS_PACK)
#define WS_IDS    3244292u  // i32 [N]
#define WS_POS    3277060u  // i32 [N]
#define WS_OFFS   3309828u  // i32 [K]
#define WS_SORTED 3342596u  // i32 [N]
#define WS_LIST   3375364u  // u32 [32*8192] worklist (tok<<5|chunk), 1 MiB
                            // end 4423940 < 5.09 MB (R4-proven ws floor)

#define CHUNK  256
#define NCHUNK (NCODE / CHUNK)  // 32
#define TILES  (CHUNK / 16)     // 16

typedef __attribute__((ext_vector_type(8))) short bf16x8;
typedef __attribute__((ext_vector_type(4))) float f32x4;

__device__ inline unsigned short f2bf(float x) {
    unsigned u = __float_as_uint(x);
    return (unsigned short)((u + 0x7FFFu + ((u >> 16) & 1u)) >> 16);
}
__device__ inline unsigned fmap(float s) {   // monotonic f32 -> u32
    unsigned u = __float_as_uint(s);
    return (u & 0x80000000u) ? ~u : (u | 0x80000000u);
}

// -------- Kernel A: blocks 0..31 token norm (zn + znbf); 32..159 emb -> ebf ----
__global__ __launch_bounds__(256) void k_prep(const float* __restrict__ z,
                                              const float* __restrict__ emb,
                                              float* __restrict__ zn,
                                              unsigned short* __restrict__ znbf,
                                              unsigned short* __restrict__ ebf) {
    if (blockIdx.x < 32) {
        int n = blockIdx.x * 256 + threadIdx.x;   // token = b*256 + hw
        int b = n >> 8, hw = n & 255;
        const float* zp = z + (size_t)b * (CDIM * HW) + hw;
        float v[CDIM];
        float ss = 0.f;
#pragma unroll
        for (int c = 0; c < CDIM; ++c) {
            float t = zp[c * HW];                 // coalesced per c
            v[c] = t;
            ss += t * t;
        }
        float d = fmaxf(sqrtf(ss), 1e-12f);
        float* o = zn + (size_t)n * CDIM;
        unsigned short* ob = znbf + (size_t)n * CDIM;
#pragma unroll
        for (int c = 0; c < CDIM; ++c) {
            float t = v[c] / d;
            o[c] = t;
            ob[c] = f2bf(t);
        }
    } else {
        int base = (blockIdx.x - 32) * 2048 + threadIdx.x * 8;
        const float4* s = (const float4*)(emb + base);
        float4 x = s[0], y = s[1];
        ushort4 u0 = {f2bf(x.x), f2bf(x.y), f2bf(x.z), f2bf(x.w)};
        ushort4 u1 = {f2bf(y.x), f2bf(y.y), f2bf(y.z), f2bf(y.w)};
        *(ushort4*)(ebf + base) = u0;
        *(ushort4*)(ebf + base + 4) = u1;
    }
}

// -------- Kernel B: MFMA scan -> pmax[chunk][tok] (no conversions, no atomics) --
__global__ __launch_bounds__(256) void k_max(const unsigned short* __restrict__ znbf,
                                             const unsigned short* __restrict__ ebf,
                                             float* __restrict__ pmax) {
    __shared__ unsigned short lbs[CHUNK * CDIM];  // 16 KiB
    __shared__ float lmax[256];
    int kbase = blockIdx.y * CHUNK;
    {   // stage bf16 chunk: 16 KiB, 64 B/thread
        const float4* src = (const float4*)(ebf + (size_t)kbase * CDIM);
        float4* dst = (float4*)lbs;
#pragma unroll
        for (int j = 0; j < 4; ++j)
            dst[threadIdx.x + j * 256] = src[threadIdx.x + j * 256];
    }
    __syncthreads();

    int wave = threadIdx.x >> 6, lane = threadIdx.x & 63;
    int col = lane & 15, quad = lane >> 4;
    int wtok = blockIdx.x * 256 + wave * 64;

    bf16x8 a[4];                                  // 4 frags = 64 tokens
#pragma unroll
    for (int f = 0; f < 4; ++f)
        a[f] = *(const bf16x8*)(znbf + (size_t)(wtok + f * 16 + col) * CDIM + quad * 8);

    const bf16x8* bl = (const bf16x8*)lbs;
    const f32x4 zero4 = {0.f, 0.f, 0.f, 0.f};
    float m[4][4];
#pragma unroll
    for (int f = 0; f < 4; ++f)
#pragma unroll
        for (int r = 0; r < 4; ++r) m[f][r] = -1e30f;

    for (int t = 0; t < TILES; ++t) {
        bf16x8 b = bl[(t * 16 + col) * 4 + quad];
#pragma unroll
        for (int f = 0; f < 4; ++f) {
            f32x4 d = __builtin_amdgcn_mfma_f32_16x16x32_bf16(a[f], b, zero4, 0, 0, 0);
#pragma unroll
            for (int r = 0; r < 4; ++r) m[f][r] = fmaxf(m[f][r], d[r]);
        }
    }
#pragma unroll
    for (int f = 0; f < 4; ++f)
#pragma unroll
        for (int r = 0; r < 4; ++r) {
            float v = m[f][r];
#pragma unroll
            for (int s = 1; s < 16; s <<= 1) v = fmaxf(v, __shfl_xor(v, s));
            if (col == 0) lmax[wave * 64 + f * 16 + quad * 4 + r] = v;
        }
    __syncthreads();
    pmax[(size_t)blockIdx.y * NTOK + blockIdx.x * 256 + threadIdx.x] = lmax[threadIdx.x];
}

// -------- Kernel C: per-token gmax; qualifying chunks -> worklist --------------
// 32 blocks x 256 thr, thread = token. One atomicAdd(cnt) per BLOCK.
__global__ __launch_bounds__(256) void k_gmax(const float* __restrict__ pmax,
                                              unsigned* __restrict__ list,
                                              unsigned* __restrict__ cnt) {
    int tok = blockIdx.x * 256 + threadIdx.x;
    float pm[NCHUNK];
    float mx = -1e30f;
#pragma unroll
    for (int ch = 0; ch < NCHUNK; ++ch) {         // coalesced per ch
        pm[ch] = pmax[(size_t)ch * NTOK + tok];
        mx = fmaxf(mx, pm[ch]);
    }
    float thr = mx - EPSF;
    int nq = 0;
#pragma unroll
    for (int ch = 0; ch < NCHUNK; ++ch) nq += (pm[ch] >= thr) ? 1 : 0;

    __shared__ int sc[256];
    int t = threadIdx.x;
    sc[t] = nq;
    __syncthreads();
    for (int d = 1; d < 256; d <<= 1) {           // Hillis-Steele inclusive
        int v = sc[t] + ((t >= d) ? sc[t - d] : 0);
        __syncthreads();
        sc[t] = v;
        __syncthreads();
    }
    int incl = sc[t];
    __shared__ unsigned base;
    if (t == 255) base = atomicAdd(cnt, (unsigned)incl);
    __syncthreads();
    unsigned w = base + (unsigned)(incl - nq);
#pragma unroll
    for (int ch = 0; ch < NCHUNK; ++ch)
        if (pm[ch] >= thr) list[w++] = ((unsigned)tok << 5) | (unsigned)ch;
}

// -------- Kernel D: exact fp32 rescore of each worklist (tok,chunk) ------------
// block per entry (grid-stride): 256 threads = the chunk's 256 codes.
__global__ __launch_bounds__(256) void k_rescore(const unsigned* __restrict__ list,
                                                 const unsigned* __restrict__ cnt,
                                                 const float* __restrict__ zn,
                                                 const float* __restrict__ emb,
                                                 unsigned long long* __restrict__ packed) {
    __shared__ unsigned long long wk[4];
    unsigned n = cnt[0];
    if (n > 32u * 8192u) n = 32u * 8192u;
    int lane = threadIdx.x & 63, wid = threadIdx.x >> 6;
    for (unsigned e = blockIdx.x; e < n; e += gridDim.x) {
        unsigned ent = list[e];
        unsigned tok = ent >> 5, ch = ent & 31u;
        unsigned code = ch * 256u + threadIdx.x;
        const float* zp = zn + (size_t)tok * CDIM;     // uniform (broadcast)
        const float* ep = emb + (size_t)code * CDIM;
        float a0 = 0.f, a1 = 0.f, a2 = 0.f, a3 = 0.f;
#pragma unroll
        for (int j = 0; j < 8; ++j) {
            a0 = __builtin_fmaf(zp[4 * j + 0], ep[4 * j + 0], a0);
            a1 = __builtin_fmaf(zp[4 * j + 1], ep[4 * j + 1], a1);
            a2 = __builtin_fmaf(zp[4 * j + 2], ep[4 * j + 2], a2);
            a3 = __builtin_fmaf(zp[4 * j + 3], ep[4 * j + 3], a3);
        }
        float s = (a0 + a1) + (a2 + a3);
        unsigned long long key = ((unsigned long long)fmap(s) << 13) |
                                 (unsigned long long)(8191u - code);
#pragma unroll
        for (int sh = 1; sh < 64; sh <<= 1) {
            unsigned long long o = __shfl_xor(key, sh);
            key = (o > key) ? o : key;
        }
        if (lane == 0) wk[wid] = key;
        __syncthreads();
        if (threadIdx.x == 0) {
            unsigned long long k0 = wk[0];
            if (wk[1] > k0) k0 = wk[1];
            if (wk[2] > k0) k0 = wk[2];
            if (wk[3] > k0) k0 = wk[3];
            atomicMax(packed + tok, k0);
        }
        __syncthreads();
    }
}

// -------- Kernel E: blocks 0..1023 = z_q gather + loss; 1024..1055 = ids/pos ---
__global__ __launch_bounds__(256) void k_postzq(const unsigned long long* __restrict__ packed,
                                                const float* __restrict__ zn,
                                                const float* __restrict__ emb,
                                                int* __restrict__ bins,
                                                int* __restrict__ ids,
                                                int* __restrict__ pos,
                                                float* __restrict__ out,
                                                float* __restrict__ loss_part) {
    if (blockIdx.x >= 1024) {                     // token per thread
        int n = (blockIdx.x - 1024) * 256 + threadIdx.x;
        int id = 8191 - (int)(packed[n] & 8191ull);
        ids[n] = id;
        out[OUT_IDS + n] = (float)id;
        pos[n] = atomicAdd(bins + id, 1);         // 8192 scattered atomics
        return;
    }
    __shared__ float lsum[4];
    int b = blockIdx.x >> 5, c = blockIdx.x & 31;
    int hw = threadIdx.x;
    int n = b * 256 + hw;
    int id = 8191 - (int)(packed[n] & 8191ull);
    float ev = emb[(size_t)id * CDIM + c];        // gather (L2)
    float zv = zn[(size_t)n * CDIM + c];          // 128B-stride gather (L2)
    out[OUT_ZQ + ((size_t)b * CDIM + c) * HW + hw] = ev;  // coalesced
    float dd = ev - zv;
    float s = dd * dd;
#pragma unroll
    for (int off = 32; off > 0; off >>= 1) s += __shfl_down(s, off);
    if ((hw & 63) == 0) lsum[hw >> 6] = s;
    __syncthreads();
    if (hw == 0)
        atomicAdd(loss_part + (blockIdx.x & 63),
                  lsum[0] + lsum[1] + lsum[2] + lsum[3]);   // 16-way contention
}

// -------- Kernel S: single-block exclusive scan of bins + place sorted ---------
__global__ __launch_bounds__(1024) void k_scanplace(const int* __restrict__ bins,
                                                    const int* __restrict__ ids,
                                                    const int* __restrict__ pos,
                                                    int* __restrict__ offs,
                                                    int* __restrict__ sorted) {
    __shared__ int sc[2][1024];
    int t = threadIdx.x;
    int loc[8];
    int s = 0;
#pragma unroll
    for (int i = 0; i < 8; ++i) {
        loc[i] = s;
        s += bins[t * 8 + i];
    }
    sc[0][t] = s;
    __syncthreads();
    int src = 0;
    for (int d = 1; d < 1024; d <<= 1) {
        sc[1 - src][t] = sc[src][t] + (t >= d ? sc[src][t - d] : 0);
        src ^= 1;
        __syncthreads();
    }
    int excl = sc[src][t] - s;
#pragma unroll
    for (int i = 0; i < 8; ++i) offs[t * 8 + i] = excl + loc[i];
    __syncthreads();
    for (int n = t; n < NTOK; n += 1024)
        sorted[offs[ids[n]] + pos[n]] = n;
}

// -------- Kernel F: EMA update via segment gather + renormalize + loss ---------
__global__ __launch_bounds__(256) void k_update(const float* __restrict__ zn,
                                                const float* __restrict__ emb,
                                                const float* __restrict__ cs,
                                                const int* __restrict__ bins,
                                                const int* __restrict__ offs,
                                                const int* __restrict__ sorted,
                                                const float* __restrict__ loss_part,
                                                float* __restrict__ out) {
    int idx = blockIdx.x * 256 + threadIdx.x;
    if (blockIdx.x == 0 && threadIdx.x < 64) {    // loss finalize (wave 0)
        float lp = loss_part[threadIdx.x];
#pragma unroll
        for (int sh = 32; sh > 0; sh >>= 1) lp += __shfl_down(lp, sh);
        if (threadIdx.x == 0) out[OUT_LOSS] = lp * (1.0f / 262144.0f);
    }
    int k = idx >> 5, c = idx & 31;
    int bi = bins[k];
    int off = offs[k];
    float t = 0.f;
    for (int i = 0; i < bi; ++i) {                // avg 1 iter
        int n = sorted[off + i];
        t += zn[(size_t)n * CDIM + c];            // coalesced 128B row
    }
    float bf = (float)bi;
    bool zero = (bi == 0);
    t /= (zero ? 1.0f : bf);
    float ss = t * t;
#pragma unroll
    for (int s = 1; s < 32; s <<= 1) ss += __shfl_xor(ss, s);
    float d = fmaxf(sqrtf(ss), 1e-12f);
    float ew = emb[idx];
    float en = zero ? ew : (t / d);
    float w = ew * DECAYF + (1.0f - DECAYF) * en;
    float ss2 = w * w;
#pragma unroll
    for (int s = 1; s < 32; s <<= 1) ss2 += __shfl_xor(ss2, s);
    float d2 = fmaxf(sqrtf(ss2), 1e-12f);
    out[OUT_EMB + idx] = w / d2;
    if (c == 0) out[OUT_CS + k] = cs[k] * DECAYF + (1.0f - DECAYF) * bf;
}

extern "C" void kernel_launch(void* const* d_in, const int* in_sizes, int n_in,
                              void* d_out, int out_size, void* d_ws, size_t ws_size,
                              hipStream_t stream) {
    const float* z   = (const float*)d_in[0];   // [32,32,16,16]
    const float* emb = (const float*)d_in[1];   // [8192,32]
    const float* cs  = (const float*)d_in[2];   // [8192]
    float* out = (float*)d_out;
    char* ws = (char*)d_ws;

    float* zn                  = (float*)(ws + WS_ZN);
    unsigned short* znbf       = (unsigned short*)(ws + WS_ZNBF);
    unsigned short* ebf        = (unsigned short*)(ws + WS_EBF);
    float* pmax                = (float*)(ws + WS_PMAX);
    unsigned long long* packed = (unsigned long long*)(ws + WS_PACK);
    int* bins                  = (int*)(ws + WS_BINS);
    float* loss_part           = (float*)(ws + WS_LOSSP);
    unsigned* cnt              = (unsigned*)(ws + WS_CNT);
    int* ids                   = (int*)(ws + WS_IDS);
    int* pos                   = (int*)(ws + WS_POS);
    int* offs                  = (int*)(ws + WS_OFFS);
    int* sorted                = (int*)(ws + WS_SORTED);
    unsigned* list             = (unsigned*)(ws + WS_LIST);

    hipMemsetAsync(ws + WS_PACK, 0, WS_ZERO_BYTES, stream);

    k_prep<<<dim3(160), 256, 0, stream>>>(z, emb, zn, znbf, ebf);
    k_max<<<dim3(NTOK / 256, NCHUNK), 256, 0, stream>>>(znbf, ebf, pmax);
    k_gmax<<<dim3(NTOK / 256), 256, 0, stream>>>(pmax, list, cnt);
    k_rescore<<<dim3(512), 256, 0, stream>>>(list, cnt, zn, emb, packed);
    k_postzq<<<dim3(1056), 256, 0, stream>>>(packed, zn, emb, bins, ids, pos, out, loss_part);
    k_scanplace<<<dim3(1), 1024, 0, stream>>>(bins, ids, pos, offs, sorted);
    k_update<<<dim3(1024), 256, 0, stream>>>(zn, emb, cs, bins, offs, sorted, loss_part, out);
}

// Round 9
// 161.256 us; speedup vs baseline: 1.0151x; 1.0151x over previous
//
#include <hip/hip_runtime.h>

// NormEMAVectorQuantizer on MI355X (gfx950)
// N=8192 tokens, C=32, K=8192 codes, B=32, H*W=256.
// R9: k_max (bf16-MFMA, single sweep) -> pmax[chunk][tok]. k_argmax: BLOCK
// PER TOKEN (8192 blocks): wave0 reduces gmax over 32 partials + ballots
// qualifying chunks (pmax >= gmax-eps, ~1.05/token); 256 threads rescore
// each qualifying chunk's 256 codes with exact fp32 dots (zn row is
// block-uniform -> scalar loads); block-reduce u64 (score,code) key; thread0
// STORES the winner (no atomics, no worklist, no packed memset).
// Certificate: bf16 dot err <= 2*2^-9 = 0.0078 < eps=0.01 for unit rows, so
// the chunk of the fp32 argmax (and of every tied code) always qualifies;
// exact fp32 rescore + (8191-code) key = numpy lowest-index tie-break.
//
// Outputs (float32, concatenated):
//   [0 .. 262144)        z_q_out [B,C,H,W]
//   [262144]             loss (scalar)
//   [262145 .. 270337)   token_ids [B,H,W] as float
//   [270337 .. 532481)   new_embedding [K,C]
//   [532481 .. 540673)   new_cluster_sizes [K]

#define NTOK   8192
#define NCODE  8192
#define CDIM   32
#define HW     256
#define DECAYF 0.99f
#define EPSF   0.01f

#define OUT_ZQ   0
#define OUT_LOSS 262144
#define OUT_IDS  262145
#define OUT_EMB  270337
#define OUT_CS   532481

// workspace byte offsets
#define WS_ZN     0u        // zn row-major [N,C] f32   = 1048576
#define WS_ZNBF   1048576u  // bf16 [N,C]               = 524288
#define WS_EBF    1572864u  // bf16 [K,C]               = 524288
#define WS_PMAX   2097152u  // f32 [32][N]              = 1048576
#define WS_BINS   3145728u  // i32 [K]                  = 32768  <- zeroed
#define WS_LOSSP  3178496u  // f32 [64]                 = 256
#define WS_ZEND   3178752u
#define WS_ZERO_BYTES (WS_ZEND - WS_BINS)
#define WS_IDS    3178752u  // i32 [N]
#define WS_POS    3211520u  // i32 [N]
#define WS_OFFS   3244288u  // i32 [K]
#define WS_SORTED 3277056u  // i32 [N]   (end 3309824 < ws floor)

#define CHUNK  256
#define NCHUNK (NCODE / CHUNK)  // 32
#define TILES  (CHUNK / 16)     // 16

typedef __attribute__((ext_vector_type(8))) short bf16x8;
typedef __attribute__((ext_vector_type(4))) float f32x4;

__device__ inline unsigned short f2bf(float x) {
    unsigned u = __float_as_uint(x);
    return (unsigned short)((u + 0x7FFFu + ((u >> 16) & 1u)) >> 16);
}
__device__ inline unsigned fmap(float s) {   // monotonic f32 -> u32
    unsigned u = __float_as_uint(s);
    return (u & 0x80000000u) ? ~u : (u | 0x80000000u);
}

// -------- Kernel A: blocks 0..31 token norm (zn + znbf); 32..159 emb -> ebf ----
__global__ __launch_bounds__(256) void k_prep(const float* __restrict__ z,
                                              const float* __restrict__ emb,
                                              float* __restrict__ zn,
                                              unsigned short* __restrict__ znbf,
                                              unsigned short* __restrict__ ebf) {
    if (blockIdx.x < 32) {
        int n = blockIdx.x * 256 + threadIdx.x;   // token = b*256 + hw
        int b = n >> 8, hw = n & 255;
        const float* zp = z + (size_t)b * (CDIM * HW) + hw;
        float v[CDIM];
        float ss = 0.f;
#pragma unroll
        for (int c = 0; c < CDIM; ++c) {
            float t = zp[c * HW];                 // coalesced per c
            v[c] = t;
            ss += t * t;
        }
        float d = fmaxf(sqrtf(ss), 1e-12f);
        float* o = zn + (size_t)n * CDIM;
        unsigned short* ob = znbf + (size_t)n * CDIM;
#pragma unroll
        for (int c = 0; c < CDIM; ++c) {
            float t = v[c] / d;
            o[c] = t;
            ob[c] = f2bf(t);
        }
    } else {
        int base = (blockIdx.x - 32) * 2048 + threadIdx.x * 8;
        const float4* s = (const float4*)(emb + base);
        float4 x = s[0], y = s[1];
        ushort4 u0 = {f2bf(x.x), f2bf(x.y), f2bf(x.z), f2bf(x.w)};
        ushort4 u1 = {f2bf(y.x), f2bf(y.y), f2bf(y.z), f2bf(y.w)};
        *(ushort4*)(ebf + base) = u0;
        *(ushort4*)(ebf + base + 4) = u1;
    }
}

// -------- Kernel B: MFMA scan -> pmax[chunk][tok] (no conversions, no atomics) --
__global__ __launch_bounds__(256) void k_max(const unsigned short* __restrict__ znbf,
                                             const unsigned short* __restrict__ ebf,
                                             float* __restrict__ pmax) {
    __shared__ unsigned short lbs[CHUNK * CDIM];  // 16 KiB
    __shared__ float lmax[256];
    int kbase = blockIdx.y * CHUNK;
    {   // stage bf16 chunk: 16 KiB, 64 B/thread
        const float4* src = (const float4*)(ebf + (size_t)kbase * CDIM);
        float4* dst = (float4*)lbs;
#pragma unroll
        for (int j = 0; j < 4; ++j)
            dst[threadIdx.x + j * 256] = src[threadIdx.x + j * 256];
    }
    __syncthreads();

    int wave = threadIdx.x >> 6, lane = threadIdx.x & 63;
    int col = lane & 15, quad = lane >> 4;
    int wtok = blockIdx.x * 256 + wave * 64;

    bf16x8 a[4];                                  // 4 frags = 64 tokens
#pragma unroll
    for (int f = 0; f < 4; ++f)
        a[f] = *(const bf16x8*)(znbf + (size_t)(wtok + f * 16 + col) * CDIM + quad * 8);

    const bf16x8* bl = (const bf16x8*)lbs;
    const f32x4 zero4 = {0.f, 0.f, 0.f, 0.f};
    float m[4][4];
#pragma unroll
    for (int f = 0; f < 4; ++f)
#pragma unroll
        for (int r = 0; r < 4; ++r) m[f][r] = -1e30f;

    for (int t = 0; t < TILES; ++t) {
        bf16x8 b = bl[(t * 16 + col) * 4 + quad];
#pragma unroll
        for (int f = 0; f < 4; ++f) {
            f32x4 d = __builtin_amdgcn_mfma_f32_16x16x32_bf16(a[f], b, zero4, 0, 0, 0);
#pragma unroll
            for (int r = 0; r < 4; ++r) m[f][r] = fmaxf(m[f][r], d[r]);
        }
    }
#pragma unroll
    for (int f = 0; f < 4; ++f)
#pragma unroll
        for (int r = 0; r < 4; ++r) {
            float v = m[f][r];
#pragma unroll
            for (int s = 1; s < 16; s <<= 1) v = fmaxf(v, __shfl_xor(v, s));
            if (col == 0) lmax[wave * 64 + f * 16 + quad * 4 + r] = v;
        }
    __syncthreads();
    pmax[(size_t)blockIdx.y * NTOK + blockIdx.x * 256 + threadIdx.x] = lmax[threadIdx.x];
}

// -------- Kernel C: fused gmax + exact rescore; BLOCK PER TOKEN ----------------
__global__ __launch_bounds__(256) void k_argmax(const float* __restrict__ pmax,
                                                const float* __restrict__ zn,
                                                const float* __restrict__ emb,
                                                int* __restrict__ bins,
                                                int* __restrict__ ids,
                                                int* __restrict__ pos,
                                                float* __restrict__ out) {
    int tok = blockIdx.x;
    __shared__ unsigned sqmask;
    __shared__ unsigned long long wk[4];
    int t = threadIdx.x;
    int lane = t & 63, wid = t >> 6;

    if (wid == 0) {                               // wave 0: gmax + chunk mask
        float pm = (lane < NCHUNK) ? pmax[(size_t)lane * NTOK + tok] : -1e30f;
        float mx = pm;
#pragma unroll
        for (int s = 1; s < 64; s <<= 1) mx = fmaxf(mx, __shfl_xor(mx, s));
        unsigned long long bal = __ballot(pm >= mx - EPSF);
        if (lane == 0) sqmask = (unsigned)(bal & 0xFFFFFFFFull);
    }
    __syncthreads();
    unsigned qmask = sqmask;                      // ~1.05 bits set

    const float* zp = zn + (size_t)tok * CDIM;    // block-uniform -> scalar loads
    unsigned long long bestkey = 0;
    while (qmask) {
        int ch = __ffs(qmask) - 1;
        qmask &= qmask - 1;
        int code = ch * 256 + t;
        const float* ep = emb + (size_t)code * CDIM;
        float a0 = 0.f, a1 = 0.f, a2 = 0.f, a3 = 0.f;
#pragma unroll
        for (int j = 0; j < 8; ++j) {
            a0 = __builtin_fmaf(zp[4 * j + 0], ep[4 * j + 0], a0);
            a1 = __builtin_fmaf(zp[4 * j + 1], ep[4 * j + 1], a1);
            a2 = __builtin_fmaf(zp[4 * j + 2], ep[4 * j + 2], a2);
            a3 = __builtin_fmaf(zp[4 * j + 3], ep[4 * j + 3], a3);
        }
        float s = (a0 + a1) + (a2 + a3);
        unsigned long long key = ((unsigned long long)fmap(s) << 13) |
                                 (unsigned long long)(8191 - code);
        if (key > bestkey) bestkey = key;
    }
    // block-reduce max key
#pragma unroll
    for (int sh = 1; sh < 64; sh <<= 1) {
        unsigned long long o = __shfl_xor(bestkey, sh);
        if (o > bestkey) bestkey = o;
    }
    if (lane == 0) wk[wid] = bestkey;
    __syncthreads();
    if (t == 0) {
        unsigned long long k0 = wk[0];
        if (wk[1] > k0) k0 = wk[1];
        if (wk[2] > k0) k0 = wk[2];
        if (wk[3] > k0) k0 = wk[3];
        int id = 8191 - (int)(k0 & 8191ull);
        ids[tok] = id;
        out[OUT_IDS + tok] = (float)id;
        pos[tok] = atomicAdd(bins + id, 1);       // 8192 scattered atomics total
    }
}

// -------- Kernel D: z_q gather + transpose-out + loss partials -----------------
// block = (b, c) pair: 1024 blocks x 256 hw-threads.
__global__ __launch_bounds__(256) void k_zq(const int* __restrict__ ids,
                                            const float* __restrict__ zn,
                                            const float* __restrict__ emb,
                                            float* __restrict__ out,
                                            float* __restrict__ loss_part) {
    __shared__ float lsum[4];
    int b = blockIdx.x >> 5, c = blockIdx.x & 31;
    int hw = threadIdx.x;
    int n = b * 256 + hw;
    int id = ids[n];
    float ev = emb[(size_t)id * CDIM + c];        // gather (L2)
    float zv = zn[(size_t)n * CDIM + c];          // 128B-stride (L2)
    out[OUT_ZQ + ((size_t)b * CDIM + c) * HW + hw] = ev;  // coalesced
    float dd = ev - zv;
    float s = dd * dd;
#pragma unroll
    for (int off = 32; off > 0; off >>= 1) s += __shfl_down(s, off);
    if ((hw & 63) == 0) lsum[hw >> 6] = s;
    __syncthreads();
    if (hw == 0)
        atomicAdd(loss_part + (blockIdx.x & 63),
                  lsum[0] + lsum[1] + lsum[2] + lsum[3]);
}

// -------- Kernel S: single-block scan of bins (wave-shuffle) + place sorted ----
__global__ __launch_bounds__(1024) void k_scanplace(const int* __restrict__ bins,
                                                    const int* __restrict__ ids,
                                                    const int* __restrict__ pos,
                                                    int* __restrict__ offs,
                                                    int* __restrict__ sorted) {
    __shared__ int wtot[16], wexcl[16];
    int t = threadIdx.x;
    int lane = t & 63, wid = t >> 6;
    int loc[8];
    int s = 0;
#pragma unroll
    for (int i = 0; i < 8; ++i) {                 // local exclusive prefix
        loc[i] = s;
        s += bins[t * 8 + i];
    }
    int v = s;                                    // wave-inclusive scan
#pragma unroll
    for (int sh = 1; sh < 64; sh <<= 1) {
        int o = __shfl_up(v, sh);
        if (lane >= sh) v += o;
    }
    if (lane == 63) wtot[wid] = v;
    __syncthreads();
    if (t < 16) {                                 // scan 16 wave totals
        int w = wtot[t];
        int iv = w;
#pragma unroll
        for (int sh = 1; sh < 16; sh <<= 1) {
            int o = __shfl_up(iv, sh);
            if (t >= sh) iv += o;
        }
        wexcl[t] = iv - w;
    }
    __syncthreads();
    int excl = wexcl[wid] + (v - s);              // global exclusive for thread
#pragma unroll
    for (int i = 0; i < 8; ++i) offs[t * 8 + i] = excl + loc[i];
    __syncthreads();
    for (int n = t; n < NTOK; n += 1024)
        sorted[offs[ids[n]] + pos[n]] = n;
}

// -------- Kernel F: EMA update via segment gather + renormalize + loss ---------
__global__ __launch_bounds__(256) void k_update(const float* __restrict__ zn,
                                                const float* __restrict__ emb,
                                                const float* __restrict__ cs,
                                                const int* __restrict__ bins,
                                                const int* __restrict__ offs,
                                                const int* __restrict__ sorted,
                                                const float* __restrict__ loss_part,
                                                float* __restrict__ out) {
    int idx = blockIdx.x * 256 + threadIdx.x;
    if (blockIdx.x == 0 && threadIdx.x < 64) {    // loss finalize (wave 0)
        float lp = loss_part[threadIdx.x];
#pragma unroll
        for (int sh = 32; sh > 0; sh >>= 1) lp += __shfl_down(lp, sh);
        if (threadIdx.x == 0) out[OUT_LOSS] = lp * (1.0f / 262144.0f);
    }
    int k = idx >> 5, c = idx & 31;
    int bi = bins[k];
    int off = offs[k];
    float t = 0.f;
    for (int i = 0; i < bi; ++i) {                // avg 1 iter
        int n = sorted[off + i];
        t += zn[(size_t)n * CDIM + c];            // coalesced 128B row
    }
    float bf = (float)bi;
    bool zero = (bi == 0);
    t /= (zero ? 1.0f : bf);
    float ss = t * t;
#pragma unroll
    for (int s = 1; s < 32; s <<= 1) ss += __shfl_xor(ss, s);
    float d = fmaxf(sqrtf(ss), 1e-12f);
    float ew = emb[idx];
    float en = zero ? ew : (t / d);
    float w = ew * DECAYF + (1.0f - DECAYF) * en;
    float ss2 = w * w;
#pragma unroll
    for (int s = 1; s < 32; s <<= 1) ss2 += __shfl_xor(ss2, s);
    float d2 = fmaxf(sqrtf(ss2), 1e-12f);
    out[OUT_EMB + idx] = w / d2;
    if (c == 0) out[OUT_CS + k] = cs[k] * DECAYF + (1.0f - DECAYF) * bf;
}

extern "C" void kernel_launch(void* const* d_in, const int* in_sizes, int n_in,
                              void* d_out, int out_size, void* d_ws, size_t ws_size,
                              hipStream_t stream) {
    const float* z   = (const float*)d_in[0];   // [32,32,16,16]
    const float* emb = (const float*)d_in[1];   // [8192,32]
    const float* cs  = (const float*)d_in[2];   // [8192]
    float* out = (float*)d_out;
    char* ws = (char*)d_ws;

    float* zn            = (float*)(ws + WS_ZN);
    unsigned short* znbf = (unsigned short*)(ws + WS_ZNBF);
    unsigned short* ebf  = (unsigned short*)(ws + WS_EBF);
    float* pmax          = (float*)(ws + WS_PMAX);
    int* bins            = (int*)(ws + WS_BINS);
    float* loss_part     = (float*)(ws + WS_LOSSP);
    int* ids             = (int*)(ws + WS_IDS);
    int* pos             = (int*)(ws + WS_POS);
    int* offs            = (int*)(ws + WS_OFFS);
    int* sorted          = (int*)(ws + WS_SORTED);

    hipMemsetAsync(ws + WS_BINS, 0, WS_ZERO_BYTES, stream);

    k_prep<<<dim3(160), 256, 0, stream>>>(z, emb, zn, znbf, ebf);
    k_max<<<dim3(NTOK / 256, NCHUNK), 256, 0, stream>>>(znbf, ebf, pmax);
    k_argmax<<<dim3(NTOK), 256, 0, stream>>>(pmax, zn, emb, bins, ids, pos, out);
    k_zq<<<dim3(1024), 256, 0, stream>>>(ids, zn, emb, out, loss_part);
    k_scanplace<<<dim3(1), 1024, 0, stream>>>(bins, ids, pos, offs, sorted);
    k_update<<<dim3(1024), 256, 0, stream>>>(zn, emb, cs, bins, offs, sorted, loss_part, out);
}